// Round 1
// baseline (3150.824 us; speedup 1.0000x reference)
//
#include <hip/hip_runtime.h>
#include <stdint.h>

#define BSZ 256
#define SEQ 512
#define KD  2048   // ques_dim == vis_dim
#define AD  1024   // att_dim
#define M2  (BSZ*SEQ)

typedef __attribute__((ext_vector_type(8))) short s16x8;
typedef __attribute__((ext_vector_type(4))) float f32x4;

__device__ inline unsigned short f2bf(float f) {
  union { float f; unsigned u; } v; v.f = f;
  return (unsigned short)((v.u + 0x8000u) >> 16);  // round-half-up to bf16
}

__device__ inline void async_copy16(const void* g, void* l) {
  __builtin_amdgcn_global_load_lds(
      (const __attribute__((address_space(1))) unsigned int*)(uintptr_t)g,
      (__attribute__((address_space(3))) unsigned int*)(unsigned int)(uintptr_t)l,
      16, 0, 0);
}

// W[2048][1024] fp32 -> T[1024][2048] bf16 (K-major for MFMA B-operand)
__global__ __launch_bounds__(256)
void transpose_convert(const float* __restrict__ W0, const float* __restrict__ W1,
                       unsigned short* __restrict__ T0, unsigned short* __restrict__ T1) {
  const float* W = blockIdx.z ? W1 : W0;
  unsigned short* T = blockIdx.z ? T1 : T0;
  __shared__ unsigned short tile[32][33];
  int a0 = blockIdx.x * 32;            // col in W (att dim)
  int v0 = blockIdx.y * 32;            // row in W (vis/ques dim)
  int tc = threadIdx.x & 31, tr = threadIdx.x >> 5;
#pragma unroll
  for (int p = 0; p < 4; ++p) {
    int r = tr + p * 8;
    tile[tc][r] = f2bf(W[(size_t)(v0 + r) * AD + a0 + tc]);
  }
  __syncthreads();
#pragma unroll
  for (int p = 0; p < 4; ++p) {
    int r = tr + p * 8;
    T[(size_t)(a0 + r) * KD + v0 + tc] = tile[r][tc];
  }
}

// A [Mrows][2048] fp32 (Y or X), Bt [1024][2048] bf16 (K-major).
// Tile: 128(M) x 256(N), BK=32. 4 waves in 2x2; wave tile 64x128.
// EPI=0: out[m][a] = acc + bias[a]      (X2att)
// EPI=1: atomicAdd(logits[m], sum_a relu(acc + x2att[b][a]) * wmap[a])
template <int EPI>
__global__ __launch_bounds__(256)
void gemm_epilogue(const float* __restrict__ A, const unsigned short* __restrict__ Bt,
                   const float* __restrict__ x2att, const float* __restrict__ wmap,
                   const float* __restrict__ bias, float* __restrict__ out) {
  __shared__ unsigned short As[128 * 32];   // [128 m][32 k] bf16
  __shared__ unsigned short Bs[256 * 32];   // [256 n][32 k] bf16
  const int tid = threadIdx.x;
  const int w = tid >> 6, lane = tid & 63;
  const int wm = w >> 1, wn = w & 1;
  const int q = lane >> 4, r16 = lane & 15;
  const int m0 = blockIdx.y * 128, n0 = blockIdx.x * 256;

  f32x4 acc[4][8];
#pragma unroll
  for (int i = 0; i < 4; ++i)
#pragma unroll
    for (int j = 0; j < 8; ++j) acc[i][j] = (f32x4){0.f, 0.f, 0.f, 0.f};

  // A staging: thread owns 16 contiguous elems -> As[tid*16]
  const int arow = tid >> 1, acol = (tid & 1) * 16;
  const float* gA = A + (size_t)(m0 + arow) * KD + acol;
  unsigned short* lA = &As[tid * 16];

  // B staging: 1024 16B-chunks, 4 per thread, async direct-to-LDS
  const unsigned short* gB[4];
  unsigned short* lB[4];
#pragma unroll
  for (int i = 0; i < 4; ++i) {
    int ci = w * 256 + i * 64 + lane;
    gB[i] = Bt + (size_t)(n0 + (ci >> 2)) * KD + (ci & 3) * 8;
    lB[i] = &Bs[(w * 256 + i * 64) * 8];
  }

  const unsigned short* pa0 = &As[(wm * 64 + r16) * 32 + q * 8];
  const unsigned short* pb0 = &Bs[(wn * 128 + r16) * 32 + q * 8];

  for (int kt = 0; kt < KD / 32; ++kt) {
    const int k0 = kt * 32;
    float4 f0 = ((const float4*)(gA + k0))[0];
    float4 f1 = ((const float4*)(gA + k0))[1];
    float4 f2 = ((const float4*)(gA + k0))[2];
    float4 f3 = ((const float4*)(gA + k0))[3];
    __syncthreads();                    // prev compute done; LDS free
#pragma unroll
    for (int i = 0; i < 4; ++i) async_copy16(gB[i] + k0, lB[i]);
    s16x8 sa, sb;
    sa[0] = (short)f2bf(f0.x); sa[1] = (short)f2bf(f0.y);
    sa[2] = (short)f2bf(f0.z); sa[3] = (short)f2bf(f0.w);
    sa[4] = (short)f2bf(f1.x); sa[5] = (short)f2bf(f1.y);
    sa[6] = (short)f2bf(f1.z); sa[7] = (short)f2bf(f1.w);
    sb[0] = (short)f2bf(f2.x); sb[1] = (short)f2bf(f2.y);
    sb[2] = (short)f2bf(f2.z); sb[3] = (short)f2bf(f2.w);
    sb[4] = (short)f2bf(f3.x); sb[5] = (short)f2bf(f3.y);
    sb[6] = (short)f2bf(f3.z); sb[7] = (short)f2bf(f3.w);
    ((s16x8*)lA)[0] = sa;
    ((s16x8*)lA)[1] = sb;
    __builtin_amdgcn_s_waitcnt(0);      // drain global_load_lds + ds_write
    __syncthreads();
    s16x8 av[4], bv[8];
#pragma unroll
    for (int i = 0; i < 4; ++i) av[i] = *(const s16x8*)(pa0 + i * 16 * 32);
#pragma unroll
    for (int j = 0; j < 8; ++j) bv[j] = *(const s16x8*)(pb0 + j * 16 * 32);
#pragma unroll
    for (int i = 0; i < 4; ++i)
#pragma unroll
      for (int j = 0; j < 8; ++j)
        acc[i][j] = __builtin_amdgcn_mfma_f32_16x16x32_bf16(av[i], bv[j], acc[i][j], 0, 0, 0);
  }

  // C/D layout (m89-verified): col = lane&15, row = (lane>>4)*4 + reg
  if (EPI == 0) {
#pragma unroll
    for (int j = 0; j < 8; ++j) {
      int col = n0 + wn * 128 + j * 16 + r16;
      float bqv = bias[col];
#pragma unroll
      for (int i = 0; i < 4; ++i) {
        int row = m0 + wm * 64 + i * 16 + q * 4;
#pragma unroll
        for (int r = 0; r < 4; ++r)
          out[(size_t)(row + r) * AD + col] = acc[i][j][r] + bqv;
      }
    }
  } else {
    const int b = m0 >> 9;              // 512 | 128 => block within one batch
    float xv[8], wv[8];
#pragma unroll
    for (int j = 0; j < 8; ++j) {
      int a = n0 + wn * 128 + j * 16 + r16;
      xv[j] = x2att[b * AD + a];
      wv[j] = wmap[a];
    }
#pragma unroll
    for (int i = 0; i < 4; ++i) {
#pragma unroll
      for (int r = 0; r < 4; ++r) {
        float t = 0.f;
#pragma unroll
        for (int j = 0; j < 8; ++j) {
          float v = acc[i][j][r] + xv[j];
          v = fmaxf(v, 0.f);
          t = fmaf(v, wv[j], t);
        }
        t += __shfl_xor(t, 1);
        t += __shfl_xor(t, 2);
        t += __shfl_xor(t, 4);
        t += __shfl_xor(t, 8);
        if (r16 == 0)
          atomicAdd(&out[m0 + wm * 64 + i * 16 + q * 4 + r], t);
      }
    }
  }
}

__global__ __launch_bounds__(256)
void softmax_rows(const float* __restrict__ logits, float* __restrict__ wout) {
  int b = blockIdx.x, t = threadIdx.x;
  float v0 = logits[b * SEQ + t];
  float v1 = logits[b * SEQ + 256 + t];
  float m = fmaxf(v0, v1);
#pragma unroll
  for (int d = 1; d < 64; d <<= 1) m = fmaxf(m, __shfl_xor(m, d));
  __shared__ float sm[4], ssum[4];
  int wv = t >> 6, ln = t & 63;
  if (ln == 0) sm[wv] = m;
  __syncthreads();
  m = fmaxf(fmaxf(sm[0], sm[1]), fmaxf(sm[2], sm[3]));
  float e0 = __expf(v0 - m), e1 = __expf(v1 - m);
  float s = e0 + e1;
#pragma unroll
  for (int d = 1; d < 64; d <<= 1) s += __shfl_xor(s, d);
  if (ln == 0) ssum[wv] = s;
  __syncthreads();
  s = ssum[0] + ssum[1] + ssum[2] + ssum[3];
  float inv = 1.f / s;
  wout[b * SEQ + t] = e0 * inv;
  wout[b * SEQ + 256 + t] = e1 * inv;
}

// out[b][v] += sum_n w[b][n] * Y[b][n][v]; 4 n-chunks per batch, atomic combine
__global__ __launch_bounds__(256)
void weighted_sum(const float* __restrict__ Y, const float* __restrict__ w,
                  float* __restrict__ out) {
  int b = blockIdx.x >> 2, chunk = blockIdx.x & 3;
  int t = threadIdx.x;
  __shared__ float wsm[128];
  if (t < 128) wsm[t] = w[b * SEQ + chunk * 128 + t];
  __syncthreads();
  float acc[8] = {0.f, 0.f, 0.f, 0.f, 0.f, 0.f, 0.f, 0.f};
  const float* yb = Y + (size_t)b * SEQ * KD + (size_t)chunk * 128 * KD + t * 8;
  for (int n = 0; n < 128; ++n) {
    float wn = wsm[n];
    float4 y0 = ((const float4*)yb)[0];
    float4 y1 = ((const float4*)yb)[1];
    acc[0] = fmaf(wn, y0.x, acc[0]);
    acc[1] = fmaf(wn, y0.y, acc[1]);
    acc[2] = fmaf(wn, y0.z, acc[2]);
    acc[3] = fmaf(wn, y0.w, acc[3]);
    acc[4] = fmaf(wn, y1.x, acc[4]);
    acc[5] = fmaf(wn, y1.y, acc[5]);
    acc[6] = fmaf(wn, y1.z, acc[6]);
    acc[7] = fmaf(wn, y1.w, acc[7]);
    yb += KD;
  }
  float* ob = out + (size_t)b * KD + t * 8;
#pragma unroll
  for (int j = 0; j < 8; ++j) atomicAdd(&ob[j], acc[j]);
}

extern "C" void kernel_launch(void* const* d_in, const int* in_sizes, int n_in,
                              void* d_out, int out_size, void* d_ws, size_t ws_size,
                              hipStream_t stream) {
  const float* X     = (const float*)d_in[0];
  const float* Y     = (const float*)d_in[1];
  const float* Wvis  = (const float*)d_in[2];
  const float* Wques = (const float*)d_in[3];
  const float* bques = (const float*)d_in[4];
  const float* Wmap  = (const float*)d_in[5];
  // d_in[6] = b_map: softmax-shift-invariant, unused.
  float* out = (float*)d_out;

  char* ws = (char*)d_ws;
  unsigned short* Wt  = (unsigned short*)(ws);                       // 4 MB bf16 [1024][2048]
  unsigned short* Wqt = (unsigned short*)(ws + (4u << 20));          // 4 MB bf16 [1024][2048]
  float* X2att  = (float*)(ws + (8u << 20));                         // 1 MB
  float* logits = (float*)(ws + (9u << 20));                         // 512 KB
  float* wsoft  = (float*)(ws + (9u << 20) + (512u << 10));          // 512 KB

  hipMemsetAsync(logits, 0, (size_t)M2 * 4, stream);
  hipMemsetAsync(out, 0, (size_t)BSZ * KD * 4, stream);

  transpose_convert<<<dim3(AD / 32, KD / 32, 2), 256, 0, stream>>>(Wvis, Wques, Wt, Wqt);
  // X2att = X @ W_ques + b_ques   (256 rows)
  gemm_epilogue<0><<<dim3(AD / 256, BSZ / 128), 256, 0, stream>>>(
      X, Wqt, nullptr, nullptr, bques, X2att);
  // logits[m] = sum_a relu(x2att + Y@W_vis) * wmap   (131072 rows)
  gemm_epilogue<1><<<dim3(AD / 256, M2 / 128), 256, 0, stream>>>(
      Y, Wt, X2att, Wmap, nullptr, logits);
  softmax_rows<<<BSZ, 256, 0, stream>>>(logits, wsoft);
  weighted_sum<<<BSZ * 4, 256, 0, stream>>>(Y, wsoft, out);
}